// Round 1
// baseline (268.288 us; speedup 1.0000x reference)
//
#include <hip/hip_runtime.h>

// GAT edge-average forward, factored:
//   A = x @ Wf[:, :64]^T            [N,64]
//   B = x @ Wf[:, 64:]^T + bf       [N,64]   (bf folded)
//   c = x @ Ww[0, :64]              [N]
//   d = x @ Ww[0, 64:] + bw         [N]      (bw folded)
//   per edge e: a_e = c[src]+d[tgt];  y_e = relu(A[src]+B[tgt])
//   out[t] = sum_e y_e * a_e ;  asum[t] = sum_e a_e ;  out /= (asum + eps)

__global__ __launch_bounds__(256) void gat_precompute(
    const float* __restrict__ x, const float* __restrict__ Wf,
    const float* __restrict__ Ww, const float* __restrict__ bf,
    const float* __restrict__ bw,
    float* __restrict__ A, float* __restrict__ B,
    float* __restrict__ cg, float* __restrict__ dg, int N)
{
    // w2[k][dd]: dd<64 -> Wf[dd][k] (A-half); dd>=64 -> Wf[dd-64][64+k] (B-half)
    __shared__ float w2[64][132];   // pad 132: 528B row stride (16B-aligned, banks ok)
    __shared__ float xs[64][68];    // xs[k][node_local], pad 68: 272B stride
    __shared__ float ww[128];
    __shared__ float bfs[64];

    const int tid = threadIdx.x;
    for (int f = tid; f < 64 * 128; f += 256) {
        int d  = f >> 7;        // output row 0..63
        int kk = f & 127;       // input col 0..127
        w2[kk & 63][(kk >> 6) * 64 + d] = Wf[f];
    }
    if (tid < 128) ww[tid] = Ww[tid];
    if (tid < 64)  bfs[tid] = bf[tid];

    const int n0 = blockIdx.x << 6;
    for (int i = tid; i < 64 * 64; i += 256) {
        int nl = i >> 6, k = i & 63;
        int n = n0 + nl;
        xs[k][nl] = (n < N) ? x[(size_t)n * 64 + k] : 0.f;
    }
    __syncthreads();

    // 16x16 thread grid: ti -> 4 nodes, tj -> 8 output dims (of 128 combined)
    const int ti = tid & 15, tj = tid >> 4;
    float acc[4][8];
#pragma unroll
    for (int i = 0; i < 4; ++i)
#pragma unroll
        for (int j = 0; j < 8; ++j) acc[i][j] = 0.f;

#pragma unroll 4
    for (int k = 0; k < 64; ++k) {
        const float4 xv = *(const float4*)&xs[k][ti * 4];
        const float4 w0 = *(const float4*)&w2[k][tj * 8];
        const float4 w1 = *(const float4*)&w2[k][tj * 8 + 4];
        const float xa[4] = {xv.x, xv.y, xv.z, xv.w};
        const float wa[8] = {w0.x, w0.y, w0.z, w0.w, w1.x, w1.y, w1.z, w1.w};
#pragma unroll
        for (int i = 0; i < 4; ++i)
#pragma unroll
            for (int j = 0; j < 8; ++j)
                acc[i][j] = fmaf(xa[i], wa[j], acc[i][j]);
    }

#pragma unroll
    for (int i = 0; i < 4; ++i) {
        const int n = n0 + ti * 4 + i;
        if (n < N) {
            if (tj < 8) {
#pragma unroll
                for (int j = 0; j < 8; ++j)
                    A[(size_t)n * 64 + tj * 8 + j] = acc[i][j];
            } else {
#pragma unroll
                for (int j = 0; j < 8; ++j) {
                    int d2 = (tj - 8) * 8 + j;
                    B[(size_t)n * 64 + d2] = acc[i][j] + bfs[d2];
                }
            }
        }
    }

    // attention scalars c,d (xs untouched since the sync)
    if (tid < 64) {
        const int n = n0 + tid;
        if (n < N) {
            float sc = 0.f, sd = 0.f;
            for (int k = 0; k < 64; ++k) {
                const float xv = xs[k][tid];
                sc = fmaf(xv, ww[k], sc);
                sd = fmaf(xv, ww[64 + k], sd);
            }
            cg[n] = sc;
            dg[n] = sd + bw[0];
        }
    }
}

__global__ __launch_bounds__(256) void gat_edge(
    const int* __restrict__ src, const int* __restrict__ tgt,
    const float* __restrict__ A, const float* __restrict__ B,
    const float* __restrict__ cg, const float* __restrict__ dg,
    float* __restrict__ out, float* __restrict__ asum, int E)
{
    const int d  = threadIdx.x & 63;                                // lane = output dim
    const int w  = blockIdx.x * (blockDim.x >> 6) + (threadIdx.x >> 6);
    const int nw = gridDim.x * (blockDim.x >> 6);
    for (int e = w; e < E; e += nw) {
        const int s = src[e];
        const int t = tgt[e];
        const float a_e = cg[s] + dg[t];                            // bw folded in dg
        const float y = fmaxf(A[(size_t)s * 64 + d] + B[(size_t)t * 64 + d], 0.f);
        atomicAdd(&out[(size_t)t * 64 + d], y * a_e);
        if (d == 0) atomicAdd(&asum[t], a_e);
    }
}

__global__ __launch_bounds__(256) void gat_finalize(
    float* __restrict__ out, const float* __restrict__ asum, int total)
{
    const int i = blockIdx.x * blockDim.x + threadIdx.x;
    if (i < total) out[i] = out[i] / (asum[i >> 6] + 1e-6f);
}

extern "C" void kernel_launch(void* const* d_in, const int* in_sizes, int n_in,
                              void* d_out, int out_size, void* d_ws, size_t ws_size,
                              hipStream_t stream)
{
    // setup_inputs order: x, adj, src, tgt, Msrc, Wf, bf, Ww, bw
    const float* x   = (const float*)d_in[0];
    const int*   src = (const int*)d_in[2];
    const int*   tgt = (const int*)d_in[3];
    const float* Wf  = (const float*)d_in[5];
    const float* bf  = (const float*)d_in[6];
    const float* Ww  = (const float*)d_in[7];
    const float* bw  = (const float*)d_in[8];

    const int N = in_sizes[0] / 64;
    const int E = in_sizes[2];
    float* out = (float*)d_out;

    float* A    = (float*)d_ws;                 // N*64
    float* B    = A + (size_t)N * 64;           // N*64
    float* cg   = B + (size_t)N * 64;           // N
    float* dg   = cg + N;                       // N
    float* asum = dg + N;                       // N
    // total ws use: (2*64+3)*N*4 bytes ~= 26.2 MB

    hipMemsetAsync(d_out, 0, (size_t)out_size * sizeof(float), stream);
    hipMemsetAsync(asum, 0, (size_t)N * sizeof(float), stream);

    const int nb1 = (N + 63) / 64;
    gat_precompute<<<nb1, 256, 0, stream>>>(x, Wf, Ww, bf, bw, A, B, cg, dg, N);
    gat_edge<<<2048, 256, 0, stream>>>(src, tgt, A, B, cg, dg, out, asum, E);
    const int total = N * 64;
    gat_finalize<<<(total + 255) / 256, 256, 0, stream>>>(out, asum, total);
}